// Round 9
// baseline (5633.945 us; speedup 1.0000x reference)
//
#include <hip/hip_runtime.h>
#include <hip/hip_bf16.h>
#include <stdint.h>

#define T_LEN 512
#define G3 768

typedef __attribute__((ext_vector_type(8))) short short8;
typedef __attribute__((ext_vector_type(4))) float f32x4;
typedef __attribute__((ext_vector_type(2))) unsigned int uint2v;

static __device__ __forceinline__ float bf2f(unsigned short u){
  union { unsigned int i; float f; } v; v.i = ((unsigned int)u)<<16; return v.f;
}
static __device__ __forceinline__ unsigned short f2bf(float f){
  union { float f; unsigned int i; } v; v.f = f;
  unsigned int x = v.i;
  x += 0x7fffu + ((x>>16)&1u);   // RNE
  return (unsigned short)(x>>16);
}
static __device__ __forceinline__ float asf(unsigned int u){
  union { unsigned int i; float f; } v; v.i = u; return v.f;
}

#define AS1(p) ((const __attribute__((address_space(1))) unsigned int*)(uintptr_t)(p))
#define AS3(p) ((__attribute__((address_space(3))) unsigned int*)(uintptr_t)(p))

static __device__ __forceinline__ void stage16(const void* g, void* l){
  __builtin_amdgcn_global_load_lds(AS1(g), AS3(l), 16, 0, 0);
}

#define L2E 1.4426950408889634f

// ---------------- converts ----------------
__global__ void k_cvt(const float* __restrict__ s, unsigned short* __restrict__ d, long n){
  long i = (long)blockIdx.x*blockDim.x + threadIdx.x;
  const long st = (long)gridDim.x*blockDim.x;
  for(; i<n; i+=st) d[i] = f2bf(s[i]);
}

// W_hh -> per-(layer,dir,wave) MFMA B-fragment order: [l][dir][w][tau][kt][lane][e]
// PRESCALED: r,z gates (tau<4) by -log2(e); n gate (tau>=4) by +2*log2(e).
__global__ void k_prep_whh(const float* __restrict__ w0, const float* __restrict__ wrest,
                           unsigned short* __restrict__ dst){
  const int idx = blockIdx.x*blockDim.x + threadIdx.x;
  if(idx >= 294912) return;
  const int lane = idx & 63; int t1 = idx >> 6;
  const int kt  = t1 & 7; t1 >>= 3;
  const int tau = t1 % 6; t1 /= 6;
  const int w   = t1 & 7; t1 >>= 3;
  const int dv  = t1 & 1; t1 >>= 1;
  const int l   = t1;
  const int g = tau>>1, sj = tau&1;
  const int n  = g*256 + w*32 + sj*16 + (lane&15);
  const int k0 = kt*32 + (lane>>4)*8;
  const float sc = (tau < 4) ? -L2E : (2.f*L2E);
  const float* src = (l==0) ? (w0 + (size_t)dv*G3*256)
                            : (wrest + ((size_t)((l-1)*2 + dv))*G3*256);
  const float* sp = src + (size_t)n*256 + k0;
  unsigned short* dp = dst + (size_t)idx*8;
  #pragma unroll
  for(int e=0;e<8;e++) dp[e] = f2bf(sp[e]*sc);
}

// ---------------- gx GEMM:  gx = A(bf16)[M,K] @ W(bf16)[1536,K]^T + bias ----------------
// bias = b_ih (+ b_hh for r,z) ; result prescaled per gate (-L2E / -L2E / +2*L2E).
template<int K>
__global__ __launch_bounds__(256,2) void k_gemm(
    const unsigned short* __restrict__ A,
    const unsigned short* __restrict__ Bw,
    const float* __restrict__ bias,
    const float* __restrict__ bhh2,
    unsigned short* __restrict__ gx)
{
  __shared__ __align__(16) unsigned short As[8192];
  __shared__ __align__(16) unsigned short Bs[8192];
  const int tid = threadIdx.x;
  const int lane = tid & 63, wid = tid >> 6;
  const int l15 = lane & 15, lg = lane >> 4;
  const int wm = wid >> 1, wn = wid & 1;
  const int bm = blockIdx.x, bn = blockIdx.y;
  f32x4 acc[4][4] = {};
  for(int ko=0; ko<K/64; ++ko){
    __syncthreads();
    #pragma unroll
    for(int c=0;c<4;c++){
      const int p = c*4096 + tid*16;      // byte slot in 16KB tile
      const int row = p>>7, off = p&127;
      const int swz = off ^ ((row&7)<<4); // pre-swizzled global source, linear LDS dest
      stage16(A  + (size_t)(bm*128+row)*K + ko*64 + (swz>>1), (char*)As + c*4096 + wid*1024);
      stage16(Bw + (size_t)(bn*128+row)*K + ko*64 + (swz>>1), (char*)Bs + c*4096 + wid*1024);
    }
    __syncthreads();
    #pragma unroll
    for(int kt=0;kt<2;kt++){
      short8 av[4], bv[4];
      #pragma unroll
      for(int mi=0;mi<4;mi++){
        const int row = wm*64 + mi*16 + l15;
        const int kb  = kt*64 + lg*16;
        av[mi] = *(const short8*)((const char*)As + row*128 + (kb ^ ((row&7)<<4)));
      }
      #pragma unroll
      for(int ni=0;ni<4;ni++){
        const int row = wn*64 + ni*16 + l15;
        const int kb  = kt*64 + lg*16;
        bv[ni] = *(const short8*)((const char*)Bs + row*128 + (kb ^ ((row&7)<<4)));
      }
      #pragma unroll
      for(int mi=0;mi<4;mi++)
        #pragma unroll
        for(int ni=0;ni<4;ni++)
          acc[mi][ni] = __builtin_amdgcn_mfma_f32_16x16x32_bf16(av[mi], bv[ni], acc[mi][ni], 0,0,0);
    }
  }
  // epilogue: (acc + bias) * gate_scale -> bf16, permuted store
  #pragma unroll
  for(int ni=0;ni<4;ni++){
    const int n0 = bn*128 + wn*64 + ni*16;
    const int dir = n0/768, c768 = n0%768;
    const int g = c768>>8, u = c768&255, ww = u>>5, sj = (u>>4)&1;
    float bv = bias[n0 + l15];
    if(g < 2) bv += bhh2[n0 + l15];     // fold b_hh for r,z gates
    const float scg = (g < 2) ? -L2E : (2.f*L2E);
    bv *= scg;
    #pragma unroll
    for(int mi=0;mi<4;mi++){
      const int chunk = wm*4 + mi;
      const size_t off = ((((size_t)bm*2 + dir)*8 + chunk)*12288)
                       + (size_t)(ww*3+g)*512 + (size_t)lane*8 + sj*4;
      uint2v pk;
      pk[0] = (unsigned int)f2bf(__builtin_fmaf(acc[mi][ni][0],scg,bv))
            | ((unsigned int)f2bf(__builtin_fmaf(acc[mi][ni][1],scg,bv))<<16);
      pk[1] = (unsigned int)f2bf(__builtin_fmaf(acc[mi][ni][2],scg,bv))
            | ((unsigned int)f2bf(__builtin_fmaf(acc[mi][ni][3],scg,bv))<<16);
      *(uint2v*)(gx + off) = pk;
    }
  }
}

// ---------------- recurrence: 16 WGs = 2 dir x 8 batch-chunks, 8 waves each ----------------
// r4 structure + triple-buffered gx (2-step-deep prefetch) + counted vmcnt.
template<int LAST>
__global__ __launch_bounds__(512,2) void k_rec(
    const unsigned short* __restrict__ gx,
    const unsigned short* __restrict__ wf,    // layer base of permuted W_hh (prescaled)
    const float* __restrict__ bhhL,           // [2][768] (raw)
    const float* __restrict__ h0L,            // [2][128][256]
    unsigned short* __restrict__ outb,        // bf16 out (layers 0..4)
    float* __restrict__ outf)                 // f32 d_out (layer 5)
{
  __shared__ __align__(16) unsigned short hfrag[2][4096];   // h in A-frag order, dbuf (16KB)
  __shared__ __align__(16) unsigned short gxb[3][12288];    // gx slice TRIPLE buf (72KB)
  __shared__ __align__(16) unsigned short wlds[32768];      // tau=5, kt 0-7 (64KB)
  const int tid = threadIdx.x;
  const int lane = tid & 63, w = tid >> 6;
  const int l15 = lane & 15, lg = lane >> 4, l7 = lane & 7;
  const int dir = blockIdx.x & 1, chunk = blockIdx.x >> 1;
  const unsigned short* wbase = wf + (size_t)(dir*8 + w)*24576;

  #pragma unroll
  for(int kt=0;kt<8;kt++)
    stage16(wbase + (40+kt)*512 + lane*8, &wlds[w*4096 + kt*512]);
  // prefetch gx for steps 0 AND 1; per-thread stepping pointer
  const int t0 = dir ? (T_LEN-1) : 0;
  const long gstep = dir ? -196608L : 196608L;   // elements per step (2*8*12288)
  const unsigned short* gsrc = gx + (((size_t)t0*2 + dir)*8 + chunk)*12288 + w*1536 + lane*8;
  #pragma unroll
  for(int c=0;c<3;c++) stage16(gsrc + c*512,         &gxb[0][w*1536 + c*512]);
  #pragma unroll
  for(int c=0;c<3;c++) stage16(gsrc + gstep + c*512, &gxb[1][w*1536 + c*512]);
  const unsigned short* gpre = gsrc + 2*gstep;

  short8 wr[4][8];          // tau 0-3, all kt
  short8 wr4[8];            // tau 4, all kt
  #pragma unroll
  for(int tau=0;tau<4;tau++)
    #pragma unroll
    for(int kt=0;kt<8;kt++)
      wr[tau][kt] = *(const short8*)(wbase + (tau*8+kt)*512 + (size_t)lane*8);
  #pragma unroll
  for(int kt=0;kt<8;kt++)
    wr4[kt] = *(const short8*)(wbase + (32+kt)*512 + (size_t)lane*8);

  f32x4 bh4[2];
  #pragma unroll
  for(int jt=0;jt<2;jt++){
    const float b = bhhL[dir*768 + 512 + w*32 + jt*16 + l15] * (2.f*L2E);
    #pragma unroll
    for(int e=0;e<4;e++) bh4[jt][e] = b;
  }

  float hprev[2][4];
  #pragma unroll
  for(int jt=0;jt<2;jt++)
    #pragma unroll
    for(int i=0;i<4;i++){
      const int b = chunk*16 + 4*lg + i;
      const int j = w*32 + jt*16 + l15;
      const float v = h0L[(size_t)dir*32768 + (size_t)b*256 + j];
      hprev[jt][i] = v;
      const int lp = (4*lg + i) | (((l15>>3) + 2*jt)<<4);
      hfrag[0][(w*64+lp)*8 + l7] = f2bf(v);
    }

  // LDS byte offset of this thread's hfrag write base (jt=0, i=0)
  const unsigned hf0 = (unsigned)(uintptr_t)AS3(&hfrag[0][0]);
  const unsigned hwbase = hf0 + (unsigned)(w*1024 + ((4*lg)|((l15>>3)<<4))*16 + l7*2);

  // output pointers (store of step s-1's h happens at step s; flush after loop)
  const long obase = ((long)(dir ? (T_LEN-1) : 0)*128 + chunk*16 + l15)*512
                   + dir*256 + w*32 + lg*8;
  const long ostep = dir ? -65536L : 65536L;     // elements per step (128*512)
  unsigned short* op16 = outb + obase;
  float*          op32 = outf + obase;
  __syncthreads();   // full waitcnt drain -> wlds, gxb[0], gxb[1], hfrag[0] all ready

  const f32x4 zero4 = {0.f,0.f,0.f,0.f};
  int cur = 0;
  for(int s=0; s<T_LEN; ++s){
    const int buf = s & 1, nb = buf^1;
    f32x4 acc[6];
    acc[0]=zero4; acc[1]=zero4; acc[2]=zero4; acc[3]=zero4;
    acc[4]=bh4[0]; acc[5]=bh4[1];
    #pragma unroll
    for(int kt=0;kt<8;kt++){
      const short8 a  = *(const short8*)&hfrag[buf][(kt*64+lane)*8];
      const short8 w5 = *(const short8*)&wlds[w*4096 + kt*512 + lane*8];
      acc[0] = __builtin_amdgcn_mfma_f32_16x16x32_bf16(a, wr[0][kt], acc[0], 0,0,0);
      acc[1] = __builtin_amdgcn_mfma_f32_16x16x32_bf16(a, wr[1][kt], acc[1], 0,0,0);
      acc[2] = __builtin_amdgcn_mfma_f32_16x16x32_bf16(a, wr[2][kt], acc[2], 0,0,0);
      acc[3] = __builtin_amdgcn_mfma_f32_16x16x32_bf16(a, wr[3][kt], acc[3], 0,0,0);
      acc[4] = __builtin_amdgcn_mfma_f32_16x16x32_bf16(a, wr4[kt],   acc[4], 0,0,0);
      acc[5] = __builtin_amdgcn_mfma_f32_16x16x32_bf16(a, w5,        acc[5], 0,0,0);
    }
    // issue gx prefetch for s+2 into buffer (cur+2)%3 (freed last step)
    if(s+2 < T_LEN){
      const int nx = (cur >= 1) ? cur - 1 : 2;
      #pragma unroll
      for(int c=0;c<3;c++) stage16(gpre + c*512, &gxb[nx][w*1536 + c*512]);
    }
    gpre += gstep;
    // counted wait: gx(s) was staged 2 steps ago. Outstanding newer VMEM per wave:
    //   3x stage(s+2) + (LAST?2:1)x out-store(s-1) + 3x stage(s+1)
    if(s < T_LEN-2){
      if(LAST) asm volatile("s_waitcnt vmcnt(8)" ::: "memory");
      else     asm volatile("s_waitcnt vmcnt(7)" ::: "memory");
    } else {
      asm volatile("s_waitcnt vmcnt(0)" ::: "memory");
    }
    // fused store of previous step's h (wave's own 16B granule of hfrag[buf])
    if(s){
      const short8 hs = *(const short8*)&hfrag[buf][(w*64+lane)*8];
      if(LAST){
        f32x4 lo, hi;
        #pragma unroll
        for(int e=0;e<4;e++){ lo[e] = bf2f((unsigned short)hs[e]); hi[e] = bf2f((unsigned short)hs[e+4]); }
        *(f32x4*)op32 = lo; *(f32x4*)(op32+4) = hi;
        op32 += ostep;
      } else {
        *(short8*)op16 = hs;
        op16 += ostep;
      }
    }

    union { short8 s8; unsigned int u[4]; } gv0, gv1, gv2;
    gv0.s8 = *(const short8*)&gxb[cur][(w*3+0)*512 + lane*8];
    gv1.s8 = *(const short8*)&gxb[cur][(w*3+1)*512 + lane*8];
    gv2.s8 = *(const short8*)&gxb[cur][(w*3+2)*512 + lane*8];

    #pragma unroll
    for(int jt=0;jt<2;jt++){
      float hv[4];
      #pragma unroll
      for(int p=0;p<2;p++){
        const unsigned int dr = gv0.u[jt*2+p], dz = gv1.u[jt*2+p], dn = gv2.u[jt*2+p];
        #pragma unroll
        for(int h=0;h<2;h++){
          const int i = 2*p + h;
          const float xr = h ? asf(dr & 0xffff0000u) : asf(dr << 16);
          const float xz = h ? asf(dz & 0xffff0000u) : asf(dz << 16);
          const float xn = h ? asf(dn & 0xffff0000u) : asf(dn << 16);
          // prescaled: xr,xz,acc0..3 carry -log2e ; xn,acc4,5 carry +2log2e
          const float r  = __builtin_amdgcn_rcpf(1.f + __builtin_amdgcn_exp2f(xr + acc[0+jt][i]));
          const float z  = __builtin_amdgcn_rcpf(1.f + __builtin_amdgcn_exp2f(xz + acc[2+jt][i]));
          const float pn = __builtin_fmaf(r, acc[4+jt][i], xn);
          const float q  = __builtin_amdgcn_rcpf(1.f + __builtin_amdgcn_exp2f(pn));
          const float th = __builtin_fmaf(-2.f, q, 1.f);
          const float hvv= __builtin_fmaf(z, hprev[jt][i] - th, th);
          hprev[jt][i] = hvv;
          hv[i] = hvv;
        }
      }
      unsigned c01, c23;
      asm("v_cvt_pk_bf16_f32 %0, %1, %2" : "=v"(c01) : "v"(hv[0]), "v"(hv[1]));
      asm("v_cvt_pk_bf16_f32 %0, %1, %2" : "=v"(c23) : "v"(hv[2]), "v"(hv[3]));
      const unsigned ad = hwbase + (unsigned)(nb*8192 + jt*512);
      asm volatile("ds_write_b16 %0, %1\n\t"
                   "ds_write_b16_d16_hi %0, %1 offset:16\n\t"
                   "ds_write_b16 %0, %2 offset:32\n\t"
                   "ds_write_b16_d16_hi %0, %2 offset:48"
                   :: "v"(ad), "v"(c01), "v"(c23));
    }

    // barrier WITHOUT vmcnt drain (gx prefetches + out store stay in flight)
    asm volatile("s_waitcnt lgkmcnt(0)" ::: "memory");
    __builtin_amdgcn_s_barrier();
    __builtin_amdgcn_sched_barrier(0);
    cur = (cur == 2) ? 0 : cur + 1;
  }
  // flush last step's h (in hfrag[0] after 512 steps; pointers already at t_last)
  const short8 hs = *(const short8*)&hfrag[0][(w*64+lane)*8];
  if(LAST){
    f32x4 lo, hi;
    #pragma unroll
    for(int e=0;e<4;e++){ lo[e] = bf2f((unsigned short)hs[e]); hi[e] = bf2f((unsigned short)hs[e+4]); }
    *(f32x4*)op32 = lo; *(f32x4*)(op32+4) = hi;
  } else {
    *(short8*)op16 = hs;
  }
}

extern "C" void kernel_launch(void* const* d_in, const int* in_sizes, int n_in,
                              void* d_out, int out_size, void* d_ws, size_t ws_size,
                              hipStream_t stream) {
  (void)in_sizes; (void)n_in; (void)out_size; (void)ws_size;
  const float* x    = (const float*)d_in[0];
  const float* h0   = (const float*)d_in[1];
  const float* wih0 = (const float*)d_in[2];
  const float* whh0 = (const float*)d_in[3];
  const float* bih0 = (const float*)d_in[4];
  const float* bhh0 = (const float*)d_in[5];
  const float* wih  = (const float*)d_in[6];
  const float* whh  = (const float*)d_in[7];
  const float* bih  = (const float*)d_in[8];
  const float* bhh  = (const float*)d_in[9];
  float* outf = (float*)d_out;

  char* p = (char*)d_ws;
  unsigned short* xbf   = (unsigned short*)p; p += (size_t)65536*128*2;      // 16.8 MB
  unsigned short* wihbf = (unsigned short*)p; p += (size_t)4128768*2;        // 8.3 MB
  unsigned short* whhf  = (unsigned short*)p; p += (size_t)2359296*2;        // 4.7 MB
  unsigned short* gxbuf = (unsigned short*)p; p += (size_t)201326592;        // 201.3 MB
  // layer-output ping-pong lives inside d_out (bf16); final layer overwrites all with f32
  unsigned short* outA = (unsigned short*)d_out;
  unsigned short* outB = (unsigned short*)((char*)d_out + 67108864);
  unsigned short* outs[2] = {outA, outB};

  k_cvt<<<2048,256,0,stream>>>(x,    xbf,            (long)65536*128);
  k_cvt<<<512, 256,0,stream>>>(wih0, wihbf,          196608L);
  k_cvt<<<2048,256,0,stream>>>(wih,  wihbf+196608,   3932160L);
  k_prep_whh<<<1152,256,0,stream>>>(whh0, whh, whhf);

  for(int l=0; l<6; ++l){
    const unsigned short* Ain = (l==0) ? xbf : outs[(l-1)&1];
    const unsigned short* Bw  = (l==0) ? wihbf : (wihbf + 196608 + (size_t)(l-1)*786432);
    const float* bi = (l==0) ? bih0 : (bih + (size_t)(l-1)*1536);
    const float* bh = (l==0) ? bhh0 : (bhh + (size_t)(l-1)*1536);
    dim3 gg(512,12);
    if(l==0) k_gemm<128><<<gg,256,0,stream>>>(Ain,Bw,bi,bh,gxbuf);
    else     k_gemm<512><<<gg,256,0,stream>>>(Ain,Bw,bi,bh,gxbuf);
    if(l==5) k_rec<1><<<16,512,0,stream>>>(gxbuf, whhf + (size_t)l*393216, bh,
                                           h0 + (size_t)l*65536, nullptr, outf);
    else     k_rec<0><<<16,512,0,stream>>>(gxbuf, whhf + (size_t)l*393216, bh,
                                           h0 + (size_t)l*65536, outs[l&1], nullptr);
  }
}

// Round 10
// 5123.912 us; speedup vs baseline: 1.0995x; 1.0995x over previous
//
#include <hip/hip_runtime.h>
#include <hip/hip_bf16.h>
#include <stdint.h>

#define T_LEN 512
#define G3 768

typedef __attribute__((ext_vector_type(8))) short short8;
typedef __attribute__((ext_vector_type(4))) float f32x4;
typedef __attribute__((ext_vector_type(2))) unsigned int uint2v;

static __device__ __forceinline__ float bf2f(unsigned short u){
  union { unsigned int i; float f; } v; v.i = ((unsigned int)u)<<16; return v.f;
}
static __device__ __forceinline__ unsigned short f2bf(float f){
  union { float f; unsigned int i; } v; v.f = f;
  unsigned int x = v.i;
  x += 0x7fffu + ((x>>16)&1u);   // RNE
  return (unsigned short)(x>>16);
}
static __device__ __forceinline__ float asf(unsigned int u){
  union { unsigned int i; float f; } v; v.i = u; return v.f;
}

#define AS1(p) ((const __attribute__((address_space(1))) unsigned int*)(uintptr_t)(p))
#define AS3(p) ((__attribute__((address_space(3))) unsigned int*)(uintptr_t)(p))

static __device__ __forceinline__ void stage16(const void* g, void* l){
  __builtin_amdgcn_global_load_lds(AS1(g), AS3(l), 16, 0, 0);
}

#define L2E 1.4426950408889634f

// ---------------- converts ----------------
__global__ void k_cvt(const float* __restrict__ s, unsigned short* __restrict__ d, long n){
  long i = (long)blockIdx.x*blockDim.x + threadIdx.x;
  const long st = (long)gridDim.x*blockDim.x;
  for(; i<n; i+=st) d[i] = f2bf(s[i]);
}

// W_hh -> per-(layer,dir,wave) MFMA B-fragment order: [l][dir][w][tau][kt][lane][e]
// PRESCALED: r,z gates (tau<4) by -log2(e); n gate (tau>=4) by +2*log2(e).
__global__ void k_prep_whh(const float* __restrict__ w0, const float* __restrict__ wrest,
                           unsigned short* __restrict__ dst){
  const int idx = blockIdx.x*blockDim.x + threadIdx.x;
  if(idx >= 294912) return;
  const int lane = idx & 63; int t1 = idx >> 6;
  const int kt  = t1 & 7; t1 >>= 3;
  const int tau = t1 % 6; t1 /= 6;
  const int w   = t1 & 7; t1 >>= 3;
  const int dv  = t1 & 1; t1 >>= 1;
  const int l   = t1;
  const int g = tau>>1, sj = tau&1;
  const int n  = g*256 + w*32 + sj*16 + (lane&15);
  const int k0 = kt*32 + (lane>>4)*8;
  const float sc = (tau < 4) ? -L2E : (2.f*L2E);
  const float* src = (l==0) ? (w0 + (size_t)dv*G3*256)
                            : (wrest + ((size_t)((l-1)*2 + dv))*G3*256);
  const float* sp = src + (size_t)n*256 + k0;
  unsigned short* dp = dst + (size_t)idx*8;
  #pragma unroll
  for(int e=0;e<8;e++) dp[e] = f2bf(sp[e]*sc);
}

// ---------------- gx GEMM:  gx = A(bf16)[M,K] @ W(bf16)[1536,K]^T + bias ----------------
// bias = b_ih (+ b_hh for r,z) ; result prescaled per gate (-L2E / -L2E / +2*L2E).
template<int K>
__global__ __launch_bounds__(256,2) void k_gemm(
    const unsigned short* __restrict__ A,
    const unsigned short* __restrict__ Bw,
    const float* __restrict__ bias,
    const float* __restrict__ bhh2,
    unsigned short* __restrict__ gx)
{
  __shared__ __align__(16) unsigned short As[8192];
  __shared__ __align__(16) unsigned short Bs[8192];
  const int tid = threadIdx.x;
  const int lane = tid & 63, wid = tid >> 6;
  const int l15 = lane & 15, lg = lane >> 4;
  const int wm = wid >> 1, wn = wid & 1;
  const int bm = blockIdx.x, bn = blockIdx.y;
  f32x4 acc[4][4] = {};
  for(int ko=0; ko<K/64; ++ko){
    __syncthreads();
    #pragma unroll
    for(int c=0;c<4;c++){
      const int p = c*4096 + tid*16;      // byte slot in 16KB tile
      const int row = p>>7, off = p&127;
      const int swz = off ^ ((row&7)<<4); // pre-swizzled global source, linear LDS dest
      stage16(A  + (size_t)(bm*128+row)*K + ko*64 + (swz>>1), (char*)As + c*4096 + wid*1024);
      stage16(Bw + (size_t)(bn*128+row)*K + ko*64 + (swz>>1), (char*)Bs + c*4096 + wid*1024);
    }
    __syncthreads();
    #pragma unroll
    for(int kt=0;kt<2;kt++){
      short8 av[4], bv[4];
      #pragma unroll
      for(int mi=0;mi<4;mi++){
        const int row = wm*64 + mi*16 + l15;
        const int kb  = kt*64 + lg*16;
        av[mi] = *(const short8*)((const char*)As + row*128 + (kb ^ ((row&7)<<4)));
      }
      #pragma unroll
      for(int ni=0;ni<4;ni++){
        const int row = wn*64 + ni*16 + l15;
        const int kb  = kt*64 + lg*16;
        bv[ni] = *(const short8*)((const char*)Bs + row*128 + (kb ^ ((row&7)<<4)));
      }
      #pragma unroll
      for(int mi=0;mi<4;mi++)
        #pragma unroll
        for(int ni=0;ni<4;ni++)
          acc[mi][ni] = __builtin_amdgcn_mfma_f32_16x16x32_bf16(av[mi], bv[ni], acc[mi][ni], 0,0,0);
    }
  }
  // epilogue: (acc + bias) * gate_scale -> bf16, permuted store
  #pragma unroll
  for(int ni=0;ni<4;ni++){
    const int n0 = bn*128 + wn*64 + ni*16;
    const int dir = n0/768, c768 = n0%768;
    const int g = c768>>8, u = c768&255, ww = u>>5, sj = (u>>4)&1;
    float bv = bias[n0 + l15];
    if(g < 2) bv += bhh2[n0 + l15];     // fold b_hh for r,z gates
    const float scg = (g < 2) ? -L2E : (2.f*L2E);
    bv *= scg;
    #pragma unroll
    for(int mi=0;mi<4;mi++){
      const int chunk = wm*4 + mi;
      const size_t off = ((((size_t)bm*2 + dir)*8 + chunk)*12288)
                       + (size_t)(ww*3+g)*512 + (size_t)lane*8 + sj*4;
      uint2v pk;
      pk[0] = (unsigned int)f2bf(__builtin_fmaf(acc[mi][ni][0],scg,bv))
            | ((unsigned int)f2bf(__builtin_fmaf(acc[mi][ni][1],scg,bv))<<16);
      pk[1] = (unsigned int)f2bf(__builtin_fmaf(acc[mi][ni][2],scg,bv))
            | ((unsigned int)f2bf(__builtin_fmaf(acc[mi][ni][3],scg,bv))<<16);
      *(uint2v*)(gx + off) = pk;
    }
  }
}

// ---------------- recurrence: 16 WGs = 2 dir x 8 batch-chunks, 8 waves each ----------------
// r4-proven structure: double-buffered gx, 1-step-ahead prefetch, late stage issue,
// vmcnt(0) after MFMA (stage had barrier+MFMA phase to land -> near-free).
template<int LAST>
__global__ __launch_bounds__(512,2) void k_rec(
    const unsigned short* __restrict__ gx,
    const unsigned short* __restrict__ wf,    // layer base of permuted W_hh (prescaled)
    const float* __restrict__ bhhL,           // [2][768] (raw)
    const float* __restrict__ h0L,            // [2][128][256]
    unsigned short* __restrict__ outb,        // bf16 out (layers 0..4)
    float* __restrict__ outf)                 // f32 d_out (layer 5)
{
  __shared__ __align__(16) unsigned short hfrag[2][4096];   // h in A-frag order, dbuf (16KB)
  __shared__ __align__(16) unsigned short gxb[2][12288];    // gx slice dbuf (48KB)
  __shared__ __align__(16) unsigned short wlds[32768];      // tau=5, kt 0-7 (64KB)
  __shared__ __align__(16) unsigned short wlds2[12288];     // tau=4, kt 0-2 (24KB)
  const int tid = threadIdx.x;
  const int lane = tid & 63, w = tid >> 6;
  const int l15 = lane & 15, lg = lane >> 4, l7 = lane & 7;
  const int dir = blockIdx.x & 1, chunk = blockIdx.x >> 1;
  const unsigned short* wbase = wf + (size_t)(dir*8 + w)*24576;

  #pragma unroll
  for(int kt=0;kt<8;kt++)
    stage16(wbase + (40+kt)*512 + lane*8, &wlds[w*4096 + kt*512]);
  #pragma unroll
  for(int kt=0;kt<3;kt++)
    stage16(wbase + (32+kt)*512 + lane*8, &wlds2[w*1536 + kt*512]);
  // prefetch gx for step 0; per-thread stepping pointer
  const int t0 = dir ? (T_LEN-1) : 0;
  const unsigned short* gsrc = gx + (((size_t)t0*2 + dir)*8 + chunk)*12288 + w*1536 + lane*8;
  #pragma unroll
  for(int c=0;c<3;c++)
    stage16(gsrc + c*512, &gxb[0][w*1536 + c*512]);
  const long gstep = dir ? -196608 : 196608;   // elements per step (2*8*12288)
  gsrc += gstep;

  short8 wr[4][8];          // tau 0-3, all kt  (128 VGPR)
  short8 wr4[5];            // tau 4, kt 3-7    (20 VGPR)
  #pragma unroll
  for(int tau=0;tau<4;tau++)
    #pragma unroll
    for(int kt=0;kt<8;kt++)
      wr[tau][kt] = *(const short8*)(wbase + (tau*8+kt)*512 + (size_t)lane*8);
  #pragma unroll
  for(int j=0;j<5;j++)
    wr4[j] = *(const short8*)(wbase + (35+j)*512 + (size_t)lane*8);

  f32x4 bh4[2];
  #pragma unroll
  for(int jt=0;jt<2;jt++){
    const float b = bhhL[dir*768 + 512 + w*32 + jt*16 + l15] * (2.f*L2E);
    #pragma unroll
    for(int e=0;e<4;e++) bh4[jt][e] = b;
  }

  float hprev[2][4];
  #pragma unroll
  for(int jt=0;jt<2;jt++)
    #pragma unroll
    for(int i=0;i<4;i++){
      const int b = chunk*16 + 4*lg + i;
      const int j = w*32 + jt*16 + l15;
      const float v = h0L[(size_t)dir*32768 + (size_t)b*256 + j];
      hprev[jt][i] = v;
      const int lp = (4*lg + i) | (((l15>>3) + 2*jt)<<4);
      hfrag[0][(w*64+lp)*8 + l7] = f2bf(v);
    }

  // LDS byte offset of this thread's hfrag write base (jt=0, i=0)
  const unsigned hf0 = (unsigned)(uintptr_t)AS3(&hfrag[0][0]);
  const unsigned hwbase = hf0 + (unsigned)(w*1024 + ((4*lg)|((l15>>3)<<4))*16 + l7*2);

  // output pointers (store of step s-1's h happens at step s; flush after loop)
  const long obase = ((long)(dir ? (T_LEN-1) : 0)*128 + chunk*16 + l15)*512
                   + dir*256 + w*32 + lg*8;
  const long ostep = dir ? -65536 : 65536;     // elements per step (128*512)
  unsigned short* op16 = outb + obase;
  float*          op32 = outf + obase;
  __syncthreads();   // drains vmcnt (full s_waitcnt before barrier) -> wlds/wlds2/gxb[0] ready

  const f32x4 zero4 = {0.f,0.f,0.f,0.f};
  for(int s=0; s<T_LEN; ++s){
    const int buf = s & 1, nb = buf^1;
    f32x4 acc[6];
    acc[0]=zero4; acc[1]=zero4; acc[2]=zero4; acc[3]=zero4;
    acc[4]=bh4[0]; acc[5]=bh4[1];
    #pragma unroll
    for(int kt=0;kt<8;kt++){
      const short8 a  = *(const short8*)&hfrag[buf][(kt*64+lane)*8];
      const short8 w5 = *(const short8*)&wlds[w*4096 + kt*512 + lane*8];
      const short8 w4 = (kt<3) ? *(const short8*)&wlds2[w*1536 + kt*512 + lane*8]
                               : wr4[kt-3];
      acc[0] = __builtin_amdgcn_mfma_f32_16x16x32_bf16(a, wr[0][kt], acc[0], 0,0,0);
      acc[1] = __builtin_amdgcn_mfma_f32_16x16x32_bf16(a, wr[1][kt], acc[1], 0,0,0);
      acc[2] = __builtin_amdgcn_mfma_f32_16x16x32_bf16(a, wr[2][kt], acc[2], 0,0,0);
      acc[3] = __builtin_amdgcn_mfma_f32_16x16x32_bf16(a, wr[3][kt], acc[3], 0,0,0);
      acc[4] = __builtin_amdgcn_mfma_f32_16x16x32_bf16(a, w4,        acc[4], 0,0,0);
      acc[5] = __builtin_amdgcn_mfma_f32_16x16x32_bf16(a, w5,        acc[5], 0,0,0);
    }
    // gx[t] prefetched a full step ago; stores below are issued AFTER this wait,
    // so vmcnt(0) here never waits on a fresh store.
    asm volatile("s_waitcnt vmcnt(0)" ::: "memory");

    // fused store of previous step's h (wave's own 16B granule of hfrag[buf])
    if(s){
      const short8 hs = *(const short8*)&hfrag[buf][(w*64+lane)*8];
      if(LAST){
        f32x4 lo, hi;
        #pragma unroll
        for(int e=0;e<4;e++){ lo[e] = bf2f((unsigned short)hs[e]); hi[e] = bf2f((unsigned short)hs[e+4]); }
        *(f32x4*)op32 = lo; *(f32x4*)(op32+4) = hi;
        op32 += ostep;
      } else {
        *(short8*)op16 = hs;
        op16 += ostep;
      }
    }

    union { short8 s8; unsigned int u[4]; } gv0, gv1, gv2;
    gv0.s8 = *(const short8*)&gxb[buf][(w*3+0)*512 + lane*8];
    gv1.s8 = *(const short8*)&gxb[buf][(w*3+1)*512 + lane*8];
    gv2.s8 = *(const short8*)&gxb[buf][(w*3+2)*512 + lane*8];

    #pragma unroll
    for(int jt=0;jt<2;jt++){
      float hv[4];
      #pragma unroll
      for(int p=0;p<2;p++){
        const unsigned int dr = gv0.u[jt*2+p], dz = gv1.u[jt*2+p], dn = gv2.u[jt*2+p];
        #pragma unroll
        for(int h=0;h<2;h++){
          const int i = 2*p + h;
          const float xr = h ? asf(dr & 0xffff0000u) : asf(dr << 16);
          const float xz = h ? asf(dz & 0xffff0000u) : asf(dz << 16);
          const float xn = h ? asf(dn & 0xffff0000u) : asf(dn << 16);
          // prescaled: xr,xz,acc0..3 carry -log2e ; xn,acc4,5 carry +2log2e
          const float r  = __builtin_amdgcn_rcpf(1.f + __builtin_amdgcn_exp2f(xr + acc[0+jt][i]));
          const float z  = __builtin_amdgcn_rcpf(1.f + __builtin_amdgcn_exp2f(xz + acc[2+jt][i]));
          const float pn = __builtin_fmaf(r, acc[4+jt][i], xn);
          const float q  = __builtin_amdgcn_rcpf(1.f + __builtin_amdgcn_exp2f(pn));
          const float th = __builtin_fmaf(-2.f, q, 1.f);
          const float hvv= __builtin_fmaf(z, hprev[jt][i] - th, th);
          hprev[jt][i] = hvv;
          hv[i] = hvv;
        }
      }
      unsigned c01, c23;
      asm("v_cvt_pk_bf16_f32 %0, %1, %2" : "=v"(c01) : "v"(hv[0]), "v"(hv[1]));
      asm("v_cvt_pk_bf16_f32 %0, %1, %2" : "=v"(c23) : "v"(hv[2]), "v"(hv[3]));
      const unsigned ad = hwbase + (unsigned)(nb*8192 + jt*512);
      asm volatile("ds_write_b16 %0, %1\n\t"
                   "ds_write_b16_d16_hi %0, %1 offset:16\n\t"
                   "ds_write_b16 %0, %2 offset:32\n\t"
                   "ds_write_b16_d16_hi %0, %2 offset:48"
                   :: "v"(ad), "v"(c01), "v"(c23));
    }

    if(s+1 < T_LEN){
      #pragma unroll
      for(int c=0;c<3;c++)
        stage16(gsrc + c*512, &gxb[nb][w*1536 + c*512]);
    }
    gsrc += gstep;
    // barrier WITHOUT vmcnt drain (keep gx prefetch + store in flight)
    asm volatile("s_waitcnt lgkmcnt(0)" ::: "memory");
    __builtin_amdgcn_s_barrier();
    __builtin_amdgcn_sched_barrier(0);
  }
  // flush last step's h (in hfrag[0] after 512 steps; pointers already at t_last)
  const short8 hs = *(const short8*)&hfrag[0][(w*64+lane)*8];
  if(LAST){
    f32x4 lo, hi;
    #pragma unroll
    for(int e=0;e<4;e++){ lo[e] = bf2f((unsigned short)hs[e]); hi[e] = bf2f((unsigned short)hs[e+4]); }
    *(f32x4*)op32 = lo; *(f32x4*)(op32+4) = hi;
  } else {
    *(short8*)op16 = hs;
  }
}

extern "C" void kernel_launch(void* const* d_in, const int* in_sizes, int n_in,
                              void* d_out, int out_size, void* d_ws, size_t ws_size,
                              hipStream_t stream) {
  (void)in_sizes; (void)n_in; (void)out_size; (void)ws_size;
  const float* x    = (const float*)d_in[0];
  const float* h0   = (const float*)d_in[1];
  const float* wih0 = (const float*)d_in[2];
  const float* whh0 = (const float*)d_in[3];
  const float* bih0 = (const float*)d_in[4];
  const float* bhh0 = (const float*)d_in[5];
  const float* wih  = (const float*)d_in[6];
  const float* whh  = (const float*)d_in[7];
  const float* bih  = (const float*)d_in[8];
  const float* bhh  = (const float*)d_in[9];
  float* outf = (float*)d_out;

  char* p = (char*)d_ws;
  unsigned short* xbf   = (unsigned short*)p; p += (size_t)65536*128*2;      // 16.8 MB
  unsigned short* wihbf = (unsigned short*)p; p += (size_t)4128768*2;        // 8.3 MB
  unsigned short* whhf  = (unsigned short*)p; p += (size_t)2359296*2;        // 4.7 MB
  unsigned short* gxbuf = (unsigned short*)p; p += (size_t)201326592;        // 201.3 MB
  // layer-output ping-pong lives inside d_out (bf16); final layer overwrites all with f32
  unsigned short* outA = (unsigned short*)d_out;
  unsigned short* outB = (unsigned short*)((char*)d_out + 67108864);
  unsigned short* outs[2] = {outA, outB};

  k_cvt<<<2048,256,0,stream>>>(x,    xbf,            (long)65536*128);
  k_cvt<<<512, 256,0,stream>>>(wih0, wihbf,          196608L);
  k_cvt<<<2048,256,0,stream>>>(wih,  wihbf+196608,   3932160L);
  k_prep_whh<<<1152,256,0,stream>>>(whh0, whh, whhf);

  for(int l=0; l<6; ++l){
    const unsigned short* Ain = (l==0) ? xbf : outs[(l-1)&1];
    const unsigned short* Bw  = (l==0) ? wihbf : (wihbf + 196608 + (size_t)(l-1)*786432);
    const float* bi = (l==0) ? bih0 : (bih + (size_t)(l-1)*1536);
    const float* bh = (l==0) ? bhh0 : (bhh + (size_t)(l-1)*1536);
    dim3 gg(512,12);
    if(l==0) k_gemm<128><<<gg,256,0,stream>>>(Ain,Bw,bi,bh,gxbuf);
    else     k_gemm<512><<<gg,256,0,stream>>>(Ain,Bw,bi,bh,gxbuf);
    if(l==5) k_rec<1><<<16,512,0,stream>>>(gxbuf, whhf + (size_t)l*393216, bh,
                                           h0 + (size_t)l*65536, nullptr, outf);
    else     k_rec<0><<<16,512,0,stream>>>(gxbuf, whhf + (size_t)l*393216, bh,
                                           h0 + (size_t)l*65536, outs[l&1], nullptr);
  }
}